// Round 2
// 846.107 us; speedup vs baseline: 1.2851x; 1.2851x over previous
//
#include <hip/hip_runtime.h>
#include <hip/hip_bf16.h>
#include <cstdint>
#include <cstddef>

// Problem dims
#define BATCH 8192
#define DIN   2048
#define HID   2048
#define KDIM  4096   // D + H
#define NDIM  8192   // 4*H
#define MDIM  8192   // batch
#define BH    16777216  // BATCH*HID
#define NT    64     // K tiles of 64

typedef unsigned short u16;
typedef __bf16 bf16x8 __attribute__((ext_vector_type(8)));
typedef float  f32x4  __attribute__((ext_vector_type(4)));

// ---------- helpers ----------
__device__ __forceinline__ u16 f2bf(float f) {
    union { float f; unsigned u; } a; a.f = f;
    unsigned u = a.u;
    unsigned r = u + 0x7FFFu + ((u >> 16) & 1u);   // RNE
    return (u16)(r >> 16);
}
__device__ __forceinline__ float lo16(unsigned v) {
    union { unsigned u; float f; } a; a.u = v << 16; return a.f;
}
__device__ __forceinline__ float hi16(unsigned v) {
    union { unsigned u; float f; } a; a.u = v & 0xFFFF0000u; return a.f;
}
__device__ __forceinline__ void unpack8(uint4 p, float* f) {
    f[0] = lo16(p.x); f[1] = hi16(p.x);
    f[2] = lo16(p.y); f[3] = hi16(p.y);
    f[4] = lo16(p.z); f[5] = hi16(p.z);
    f[6] = lo16(p.w); f[7] = hi16(p.w);
}
__device__ __forceinline__ float sigm(float x) {
    return 1.0f / (1.0f + __expf(-x));
}
__device__ __forceinline__ float tanh_fast(float x) {
    return 1.0f - 2.0f / (__expf(2.0f * x) + 1.0f);
}
__device__ __forceinline__ void async16(const void* g, void* lds) {
    __builtin_amdgcn_global_load_lds(
        (const __attribute__((address_space(1))) void*)g,
        (__attribute__((address_space(3))) void*)lds,
        16, 0, 0);
}

// ---------- 1. cast/pack A = [x | h0] -> bf16 [8192, 4096] ----------
__global__ __launch_bounds__(256) void cast_A_kernel(
    const float* __restrict__ x, const float* __restrict__ h0,
    u16* __restrict__ Abf)
{
    size_t i8 = ((size_t)blockIdx.x * 256 + threadIdx.x) * 8;
    size_t row = i8 >> 12;            // / 4096
    int col = (int)(i8 & 4095);
    const float* src = (col < DIN) ? (x + row * DIN + col)
                                   : (h0 + row * HID + (col - DIN));
    float4 v0 = ((const float4*)src)[0];
    float4 v1 = ((const float4*)src)[1];
    uint4 o;
    o.x = (unsigned)f2bf(v0.x) | ((unsigned)f2bf(v0.y) << 16);
    o.y = (unsigned)f2bf(v0.z) | ((unsigned)f2bf(v0.w) << 16);
    o.z = (unsigned)f2bf(v1.x) | ((unsigned)f2bf(v1.y) << 16);
    o.w = (unsigned)f2bf(v1.z) | ((unsigned)f2bf(v1.w) << 16);
    *(uint4*)(Abf + i8) = o;
}

// ---------- 2. cast/pack W = [Wx | Wh] (gate order i,f,g,o) -> bf16 [8192, 4096] ----------
__global__ __launch_bounds__(256) void cast_W_kernel(
    const float* __restrict__ Wii, const float* __restrict__ Wif,
    const float* __restrict__ Wig, const float* __restrict__ Wio,
    const float* __restrict__ Whi, const float* __restrict__ Whf,
    const float* __restrict__ Whg, const float* __restrict__ Who,
    u16* __restrict__ Wbf)
{
    size_t i8 = ((size_t)blockIdx.x * 256 + threadIdx.x) * 8;
    size_t n = i8 >> 12;              // output row in [0, 8192)
    int k = (int)(i8 & 4095);
    int gate = (int)(n >> 11);        // 0..3 : i,f,g,o
    size_t h = n & 2047;
    const float* src;
    if (k < DIN) {
        const float* W = (gate == 0) ? Wii : (gate == 1) ? Wif : (gate == 2) ? Wig : Wio;
        src = W + h * DIN + k;
    } else {
        const float* W = (gate == 0) ? Whi : (gate == 1) ? Whf : (gate == 2) ? Whg : Who;
        src = W + h * HID + (k - DIN);
    }
    float4 v0 = ((const float4*)src)[0];
    float4 v1 = ((const float4*)src)[1];
    uint4 o;
    o.x = (unsigned)f2bf(v0.x) | ((unsigned)f2bf(v0.y) << 16);
    o.y = (unsigned)f2bf(v0.z) | ((unsigned)f2bf(v0.w) << 16);
    o.z = (unsigned)f2bf(v1.x) | ((unsigned)f2bf(v1.y) << 16);
    o.w = (unsigned)f2bf(v1.z) | ((unsigned)f2bf(v1.w) << 16);
    *(uint4*)(Wbf + i8) = o;
}

// ---------- 3. fused GEMM + LSTM epilogue ----------
// C[m,n] = sum_k A[m,k]*W[n,k] over n = {g*2048 + hb0 + [0,64)} for g=0..3,
// then i,f,g,o -> (h_t, c_t) written directly (no gates round-trip).
//
// 256(m) x 256(n=4 gates x 64 h) tile, BK=64, 8 waves (2m x 4n), 512 threads.
// Deep-pipelined 4-phase schedule with counted vmcnt (T3+T4), XOR-swizzled
// LDS (T2), setprio (T5), XCD block swizzle (T1).
//
// LDS: SM[65536] u16 = 128 KiB. K-loop: A dbuf [2][256x64] at bytes [0,64K),
// B dbuf at [64K,128K). Epilogue: reused as transposed gate tile
// [col 0..255][row 0..255] bf16, byte addr = col*512 + row*2, ^ ((col&7)<<4).
//
// Stage schedule (tile t lives in buf[t&1]):
//   u's p0: tile u+1's A1,A3,B0..B3 (6) -> buf[1-cur]  (dead since u-1 p3)
//   u's p2: tile u+2's A0,A2 (2)        -> buf[cur]    (A rows [0,64)+[128,192)
//                                                       dead after u's p1 barrier)
//   u's p3: s_waitcnt vmcnt(2) -> tile u+1 resident, u+2's 2 issues in flight.
__global__ __launch_bounds__(512, 2) void gemm_lstm_kernel(
    const u16* __restrict__ A,    // [8192, 4096]
    const u16* __restrict__ W,    // [8192, 4096]
    const float* __restrict__ c0,
    const float* __restrict__ bii, const float* __restrict__ bhi,
    const float* __restrict__ bif, const float* __restrict__ bhf,
    const float* __restrict__ big, const float* __restrict__ bhg,
    const float* __restrict__ bio, const float* __restrict__ bho,
    float* __restrict__ out)
{
    __shared__ u16 SM[65536];      // 128 KiB

    const int tid  = threadIdx.x;
    const int lane = tid & 63;
    const int wave = tid >> 6;
    const int wm   = wave >> 2;       // 0..1  (128 m-rows each)
    const int wn   = wave & 3;        // 0..3  == gate id (64 cols each)
    const int quad = lane >> 4;
    const int l16  = lane & 15;

    // XCD-aware bijective block swizzle (1024 blocks, 1024 % 8 == 0)
    const int wg = ((blockIdx.x & 7) << 7) + (blockIdx.x >> 3);
    const size_t m0  = (size_t)(wg >> 5) * 256;   // batch-row base
    const size_t hb0 = (size_t)(wg & 31) * 64;    // hidden-col base

    // ---- staging addressing (pre-swizzled global source, linear LDS dest) ----
    const int rr = tid >> 3;                       // row within 64-row issue
    const int gq = (tid & 7) ^ (rr & 7);           // source 16B granule (swizzle inv)
    const size_t offA = (m0 + rr) * (size_t)KDIM + (size_t)gq * 8;
    const size_t offB = (hb0 + rr) * (size_t)KDIM + (size_t)gq * 8;
    const int wvb = wave << 10;                    // wave byte base within 8KB issue
    char* AsB = (char*)SM;                         // A: bytes [0, 65536)
    char* BsB = (char*)SM + 65536;                 // B: bytes [65536, 131072)

    // A issue J covers m-rows [J*64,(J+1)*64); B issue J covers gate J's rows.
#define STG_A(BUF, J, K0) async16(A + offA + (size_t)(J) * 64 * KDIM + (size_t)(K0), \
                                  AsB + (BUF) * 32768 + (J) * 8192 + wvb)
#define STG_B(BUF, J, K0) async16(W + offB + (size_t)(J) * 2048 * KDIM + (size_t)(K0), \
                                  BsB + (BUF) * 32768 + (J) * 8192 + wvb)

    // prologue: tile0 fully (8 issues) + tile1's A0,A2
    STG_A(0, 0, 0); STG_A(0, 1, 0); STG_A(0, 2, 0); STG_A(0, 3, 0);
    STG_B(0, 0, 0); STG_B(0, 1, 0); STG_B(0, 2, 0); STG_B(0, 3, 0);
    STG_A(1, 0, 64); STG_A(1, 2, 64);

    f32x4 acc[8][4];
    #pragma unroll
    for (int i = 0; i < 8; ++i)
        #pragma unroll
        for (int j = 0; j < 4; ++j)
            acc[i][j] = (f32x4){0.f, 0.f, 0.f, 0.f};

    // ---- fragment read addressing (u16 units). tile-row % 8 == l16 % 8 for all
    //      frags, so the XOR term is a per-thread constant. ----
    const int a_base = (wm * 128 + l16) * 64;            // into As[cur]
    const int b_base = (wn * 64 + l16) * 64;             // into Bs[cur]
    int coff[2];
    coff[0] = (quad * 8) ^ ((l16 & 7) * 8);
    coff[1] = coff[0] ^ 32;                              // kk=1: granule ^4

    asm volatile("s_waitcnt vmcnt(2)" ::: "memory");     // tile0 resident
    __builtin_amdgcn_sched_barrier(0);
    __builtin_amdgcn_s_barrier();

    bf16x8 af[4][2], bfr[2][2];

#define LDA(MH) { _Pragma("unroll") for (int i = 0; i < 4; ++i) {                        \
                    _Pragma("unroll") for (int k = 0; k < 2; ++k)                        \
                      af[i][k] = *(const bf16x8*)&SM[cur * 16384 + a_base + ((MH)*4 + i) * 1024 + coff[k]]; } }
#define LDB(NH) { _Pragma("unroll") for (int j = 0; j < 2; ++j) {                        \
                    _Pragma("unroll") for (int k = 0; k < 2; ++k)                        \
                      bfr[j][k] = *(const bf16x8*)&SM[32768 + cur * 16384 + b_base + ((NH)*2 + j) * 1024 + coff[k]]; } }
#define MM(MH, NH) { __builtin_amdgcn_s_setprio(1);                                      \
                     _Pragma("unroll") for (int k = 0; k < 2; ++k) {                     \
                       _Pragma("unroll") for (int i = 0; i < 4; ++i) {                   \
                         _Pragma("unroll") for (int j = 0; j < 2; ++j)                   \
                           acc[(MH)*4 + i][(NH)*2 + j] =                                 \
                             __builtin_amdgcn_mfma_f32_16x16x32_bf16(                    \
                               af[i][k], bfr[j][k], acc[(MH)*4 + i][(NH)*2 + j], 0, 0, 0); } } \
                     __builtin_amdgcn_s_setprio(0); }

    #pragma unroll 2
    for (int u = 0; u < NT; ++u) {
        const int cur = u & 1;
        const int nxt = cur ^ 1;

        // ---- phase 0: quadrant (mh=0, nh=0); stage tile u+1's remaining 6 ----
        LDA(0); LDB(0);
        if (u + 1 < NT) {
            const int k1 = (u + 1) * 64;
            STG_A(nxt, 1, k1); STG_A(nxt, 3, k1);
            STG_B(nxt, 0, k1); STG_B(nxt, 1, k1);
            STG_B(nxt, 2, k1); STG_B(nxt, 3, k1);
        }
        __builtin_amdgcn_s_barrier();
        MM(0, 0);
        __builtin_amdgcn_s_barrier();

        // ---- phase 1: quadrant (mh=0, nh=1) ----
        LDB(1);
        __builtin_amdgcn_s_barrier();
        MM(0, 1);
        __builtin_amdgcn_s_barrier();

        // ---- phase 2: quadrant (mh=1, nh=0); stage tile u+2's A0,A2 into dead
        //      regions of the CURRENT buffer (A rows [0,64) and [128,192)) ----
        LDA(1); LDB(0);
        if (u + 2 < NT) {
            const int k2 = (u + 2) * 64;
            STG_A(cur, 0, k2); STG_A(cur, 2, k2);
        }
        __builtin_amdgcn_s_barrier();
        MM(1, 0);
        __builtin_amdgcn_s_barrier();

        // ---- phase 3: quadrant (mh=1, nh=1); tile boundary, counted vmcnt ----
        LDB(1);
        __builtin_amdgcn_s_barrier();
        MM(1, 1);
        if (u < NT - 2) { asm volatile("s_waitcnt vmcnt(2)" ::: "memory"); }
        else            { asm volatile("s_waitcnt vmcnt(0)" ::: "memory"); }
        __builtin_amdgcn_sched_barrier(0);
        __builtin_amdgcn_s_barrier();
    }

#undef STG_A
#undef STG_B
#undef LDA
#undef LDB
#undef MM

    // ================= fused LSTM epilogue =================
    // 1) dump acc (bf16, matching old gates round-trip numerics) into SM,
    //    transposed [col][row], XOR-swizzled: byte = (col*512+row*2) ^ ((col&7)<<4)
    char* smB = (char*)SM;
    #pragma unroll
    for (int mi = 0; mi < 8; ++mi) {
        #pragma unroll
        for (int ni = 0; ni < 4; ++ni) {
            int col  = wn * 64 + ni * 16 + l16;          // 0..255 (gate*64 + j)
            int rowb = wm * 128 + mi * 16 + quad * 4;    // 4 consecutive rows
            int addr = (col * 512 + rowb * 2) ^ ((l16 & 7) << 4);
            uint2 pk;
            pk.x = (unsigned)f2bf(acc[mi][ni][0]) | ((unsigned)f2bf(acc[mi][ni][1]) << 16);
            pk.y = (unsigned)f2bf(acc[mi][ni][2]) | ((unsigned)f2bf(acc[mi][ni][3]) << 16);
            *(uint2*)(smB + addr) = pk;
        }
    }
    __syncthreads();

    // 2) each thread: one h-column j = lane, rows wave*32 + [0,32) in 4 chunks of 8
    {
        const int jj = lane;
        const size_t hg = hb0 + jj;                      // global hidden index
        float bs0 = bii[hg] + bhi[hg];
        float bs1 = bif[hg] + bhf[hg];
        float bs2 = big[hg] + bhg[hg];
        float bs3 = bio[hg] + bho[hg];
        const int swz = (jj & 7) << 4;

        #pragma unroll
        for (int c = 0; c < 4; ++c) {
            const int r0 = wave * 32 + c * 8;
            float gi[8], gf[8], gg[8], go[8];
            unpack8(*(const uint4*)(smB + (((0 * 64 + jj) * 512 + r0 * 2) ^ swz)), gi);
            unpack8(*(const uint4*)(smB + (((1 * 64 + jj) * 512 + r0 * 2) ^ swz)), gf);
            unpack8(*(const uint4*)(smB + (((2 * 64 + jj) * 512 + r0 * 2) ^ swz)), gg);
            unpack8(*(const uint4*)(smB + (((3 * 64 + jj) * 512 + r0 * 2) ^ swz)), go);
            #pragma unroll
            for (int e = 0; e < 8; ++e) {
                size_t m = m0 + r0 + e;
                float c0v = c0[m * HID + hg];
                float vi = sigm(gi[e] + bs0);
                float vf = sigm(gf[e] + bs1);
                float vg = tanh_fast(gg[e] + bs2);
                float vo = sigm(go[e] + bs3);
                float cc = vf * c0v + vi * vg;
                out[m * HID + hg]      = vo * tanh_fast(cc);
                out[BH + m * HID + hg] = cc;
            }
        }
    }
}

// ---------- launch ----------
extern "C" void kernel_launch(void* const* d_in, const int* in_sizes, int n_in,
                              void* d_out, int out_size, void* d_ws, size_t ws_size,
                              hipStream_t stream) {
    const float* x   = (const float*)d_in[0];
    const float* h0  = (const float*)d_in[1];
    const float* c0  = (const float*)d_in[2];
    const float* Wii = (const float*)d_in[3];  const float* bii = (const float*)d_in[4];
    const float* Wif = (const float*)d_in[5];  const float* bif = (const float*)d_in[6];
    const float* Wig = (const float*)d_in[7];  const float* big = (const float*)d_in[8];
    const float* Wio = (const float*)d_in[9];  const float* bio = (const float*)d_in[10];
    const float* Whi = (const float*)d_in[11]; const float* bhi = (const float*)d_in[12];
    const float* Whf = (const float*)d_in[13]; const float* bhf = (const float*)d_in[14];
    const float* Whg = (const float*)d_in[15]; const float* bhg = (const float*)d_in[16];
    const float* Who = (const float*)d_in[17]; const float* bho = (const float*)d_in[18];
    float* out = (float*)d_out;

    // workspace layout: Abf 64MiB | Wbf 64MiB (gates buffer no longer needed)
    u16* Abf = (u16*)d_ws;
    u16* Wbf = Abf + (size_t)MDIM * KDIM;

    cast_A_kernel<<<16384, 256, 0, stream>>>(x, h0, Abf);
    cast_W_kernel<<<16384, 256, 0, stream>>>(Wii, Wif, Wig, Wio, Whi, Whf, Whg, Who, Wbf);
    gemm_lstm_kernel<<<1024, 512, 0, stream>>>(Abf, Wbf, c0,
        bii, bhi, bif, bhf, big, bhg, bio, bho, out);
}